// Round 1
// baseline (237.339 us; speedup 1.0000x reference)
//
#include <hip/hip_runtime.h>

// ConvSSM parallel scan, spatial-domain form.
// h_t = A (*) h_{t-1} + B (*) xpad_t, (*) = circular 3x3 conv on 64x64 grid
// (exactly what the reference's zero-padded rFFT product computes).
// One block per (b,c) image: h kept in LDS (double-buffered), sequential over T.

constexpr int T_STEPS = 64;
constexpr int B_DIM   = 2;
constexpr int C_DIM   = 32;
constexpr int HW      = 32;   // spatial size of x / output crop
constexpr int N       = 64;   // padded circular grid (2H x 2W)

__global__ __launch_bounds__(256)
void convssm_scan_kernel(const float* __restrict__ x_seq,  // (T,B,C,32,32)
                         const float* __restrict__ A_k,    // (C,3,3)
                         const float* __restrict__ B_k,    // (C,3,3)
                         float* __restrict__ out)          // (T,B,C,32,32)
{
    __shared__ float h0[N][N];
    __shared__ float h1[N][N];
    __shared__ float xs[N][N];   // zero-padded x_t; borders stay 0 forever

    const int bc = blockIdx.x;        // 0..63
    const int b  = bc >> 5;           // bc / 32
    const int c  = bc & 31;           // bc % 32

    const int tid = threadIdx.x;
    const int x   = tid & 63;               // lane = column
    const int y0  = (tid >> 6) << 4;        // wave id * 16: row strip start

    // 3x3 kernels for this channel (block-uniform -> scalar loads)
    float a[9], bw[9];
#pragma unroll
    for (int i = 0; i < 9; ++i) {
        a[i]  = A_k[c * 9 + i];
        bw[i] = B_k[c * 9 + i];
    }

    // init: h_{-1} = 0, xs fully zero (interior overwritten each step)
#pragma unroll
    for (int r = 0; r < 16; ++r) {
        h0[y0 + r][x] = 0.0f;
        xs[y0 + r][x] = 0.0f;
    }

    float (*hold)[N] = h0;
    float (*hnew)[N] = h1;

    const int xm1 = (x + 63) & 63;   // (x-1) mod 64
    const int xm2 = (x + 62) & 63;   // (x-2) mod 64

    const size_t img  = (size_t)HW * HW;              // 1024
    const size_t tstr = (size_t)B_DIM * C_DIM * img;  // 65536
    const float* xbase = x_seq + ((size_t)b * C_DIM + c) * img;
    float*       obase = out   + ((size_t)b * C_DIM + c) * img;

    const bool loader = (x < HW);

    for (int t = 0; t < T_STEPS; ++t) {
        // stage x_t into xs interior [0..31][0..31]
        if (loader) {
#pragma unroll
            for (int r = 0; r < 16; ++r) {
                int yy = y0 + r;
                if (yy < HW)
                    xs[yy][x] = xbase[(size_t)t * tstr + yy * HW + x];
            }
        }
        __syncthreads();   // xs ready; hold (h_{t-1}) ready

        // register sliding window: rows y-1 (r1) and y-2 (r2), cols {x,x-1,x-2}
        const int ym1 = (y0 + N - 1) & 63;
        const int ym2 = (y0 + N - 2) & 63;
        float hr1c0 = hold[ym1][x], hr1c1 = hold[ym1][xm1], hr1c2 = hold[ym1][xm2];
        float hr2c0 = hold[ym2][x], hr2c1 = hold[ym2][xm1], hr2c2 = hold[ym2][xm2];
        float sr1c0 = xs[ym1][x],   sr1c1 = xs[ym1][xm1],   sr1c2 = xs[ym1][xm2];
        float sr2c0 = xs[ym2][x],   sr2c1 = xs[ym2][xm1],   sr2c2 = xs[ym2][xm2];

#pragma unroll
        for (int r = 0; r < 16; ++r) {
            const int yy = y0 + r;   // < 64 always
            float hr0c0 = hold[yy][x], hr0c1 = hold[yy][xm1], hr0c2 = hold[yy][xm2];
            float sr0c0 = xs[yy][x],   sr0c1 = xs[yy][xm1],   sr0c2 = xs[yy][xm2];

            // out[y][x] = sum_{ky,kx} A[ky][kx]*h[(y-ky)%64][(x-kx)%64]
            //           + sum_{ky,kx} B[ky][kx]*xs[(y-ky)%64][(x-kx)%64]
            float v = a[0]*hr0c0 + a[1]*hr0c1 + a[2]*hr0c2
                    + a[3]*hr1c0 + a[4]*hr1c1 + a[5]*hr1c2
                    + a[6]*hr2c0 + a[7]*hr2c1 + a[8]*hr2c2
                    + bw[0]*sr0c0 + bw[1]*sr0c1 + bw[2]*sr0c2
                    + bw[3]*sr1c0 + bw[4]*sr1c1 + bw[5]*sr1c2
                    + bw[6]*sr2c0 + bw[7]*sr2c1 + bw[8]*sr2c2;

            hnew[yy][x] = v;
            if (yy < HW && x < HW)
                obase[(size_t)t * tstr + yy * HW + x] = v;

            // slide window down one row
            hr2c0 = hr1c0; hr2c1 = hr1c1; hr2c2 = hr1c2;
            hr1c0 = hr0c0; hr1c1 = hr0c1; hr1c2 = hr0c2;
            sr2c0 = sr1c0; sr2c1 = sr1c1; sr2c2 = sr1c2;
            sr1c0 = sr0c0; sr1c1 = sr0c1; sr1c2 = sr0c2;
        }
        __syncthreads();   // all reads of hold/xs done before next overwrite

        float (*tmp)[N] = hold; hold = hnew; hnew = tmp;
    }
}

extern "C" void kernel_launch(void* const* d_in, const int* in_sizes, int n_in,
                              void* d_out, int out_size, void* d_ws, size_t ws_size,
                              hipStream_t stream)
{
    const float* x_seq = (const float*)d_in[0];
    const float* A_k   = (const float*)d_in[1];
    const float* B_k   = (const float*)d_in[2];
    float* out = (float*)d_out;

    convssm_scan_kernel<<<dim3(B_DIM * C_DIM), dim3(256), 0, stream>>>(
        x_seq, A_k, B_k, out);
}

// Round 2
// 81.941 us; speedup vs baseline: 2.8965x; 2.8965x over previous
//
#include <hip/hip_runtime.h>

// ConvSSM parallel scan, spatial-domain form.
//   h_t = A (*) h_{t-1} + u_t,   u_t = B (*) xpad_t   ((*) = circular conv on 64x64)
// Pass 1 (full-chip parallel): u_t = B (*) xpad_t for all (t,b,c) -> d_ws.
//   u support is rows/cols 0..33 (no wrap); stored padded as [36][40] with zeros.
// Pass 2 (64 blocks): sequential scan over T with h in LDS, float4 stencil reads,
//   register sliding window, u prefetched one step ahead into registers.

constexpr int T_STEPS = 64;
constexpr int B_DIM   = 2;
constexpr int C_DIM   = 32;
constexpr int HW      = 32;   // x / output spatial size
constexpr int N       = 64;   // circular grid (2H x 2W)
constexpr int UR      = 36;   // padded u rows   (valid 0..33)
constexpr int UC      = 40;   // padded u cols   (valid 0..33)
constexpr int UIMG    = UR * UC;      // 1440 floats per image
constexpr int HSTR    = 68;   // LDS row stride in floats (16B-aligned, not mult of 64)

// ---------------- Pass 1: u = B (*) xpad, one block per (t,b,c) image -------
__global__ __launch_bounds__(256)
void convssm_pass1(const float* __restrict__ x_seq,   // (T,B,C,32,32)
                   const float* __restrict__ B_k,     // (C,3,3)
                   float* __restrict__ u)             // (T*B*C, 36, 40)
{
    __shared__ float xs[HW][HW + 1];
    const int img = blockIdx.x;          // t*64 + (b*32+c)
    const int c   = img & 31;
    const int tid = threadIdx.x;

    float bw[9];
#pragma unroll
    for (int i = 0; i < 9; ++i) bw[i] = B_k[c * 9 + i];

    const float* xg = x_seq + (size_t)img * (HW * HW);
#pragma unroll
    for (int k = 0; k < 4; ++k) {
        int idx = tid + k * 256;
        xs[idx >> 5][idx & 31] = xg[idx];
    }
    __syncthreads();

    float* ug = u + (size_t)img * UIMG;
    for (int base = tid; base < UIMG; base += 256) {
        int y = base / UC;
        int x = base - y * UC;
        float v = 0.0f;
        if (y < HW + 2 && x < HW + 2) {
#pragma unroll
            for (int ky = 0; ky < 3; ++ky) {
                int yy = y - ky;
                if (yy < 0 || yy >= HW) continue;
#pragma unroll
                for (int kx = 0; kx < 3; ++kx) {
                    int xx = x - kx;
                    if (xx < 0 || xx >= HW) continue;
                    v += bw[ky * 3 + kx] * xs[yy][xx];
                }
            }
        }
        ug[base] = v;   // zeros outside support (ws is poisoned -> must write)
    }
}

// ---------------- Pass 2: sequential scan, one block per (b,c) --------------
__global__ __launch_bounds__(256)
void convssm_scan2(const float* __restrict__ u,     // (T*B*C, 36, 40)
                   const float* __restrict__ A_k,   // (C,3,3)
                   float* __restrict__ out)         // (T,B,C,32,32)
{
    __shared__ __align__(16) float hbuf[2][N * HSTR];

    const int bc  = blockIdx.x;          // 0..63
    const int c   = bc & 31;
    const int tid = threadIdx.x;
    const int g   = tid & 15;            // col group: cols 4g..4g+3
    const int s   = tid >> 4;            // row strip: rows 4s..4s+3
    const int y0  = s * 4;
    const int xc  = g * 4;
    const int xlo = (xc + 60) & 63;      // start col of the "low" float4 (4g-4 mod 64)

    float a[9];
#pragma unroll
    for (int i = 0; i < 9; ++i) a[i] = A_k[c * 9 + i];

    // h_{-1} = 0
    for (int i = tid; i < N * HSTR; i += 256) hbuf[0][i] = 0.0f;

    const bool uok = (y0 < UR) && (xc < UC);     // this thread's 4 u rows exist
    const float* ub = u + (size_t)bc * UIMG + (size_t)y0 * UC + xc;
    const size_t ustep = (size_t)(B_DIM * C_DIM) * UIMG;   // per-t stride

    const float4 z4 = make_float4(0.f, 0.f, 0.f, 0.f);
    float4 uc0 = z4, uc1 = z4, uc2 = z4, uc3 = z4;
    if (uok) {
        uc0 = *(const float4*)(ub);
        uc1 = *(const float4*)(ub + UC);
        uc2 = *(const float4*)(ub + 2 * UC);
        uc3 = *(const float4*)(ub + 3 * UC);
    }

    float* hold = &hbuf[0][0];
    float* hnew = &hbuf[1][0];
    float* og   = out + (size_t)bc * (HW * HW);
    const size_t ostep = (size_t)(B_DIM * C_DIM) * (HW * HW);

    __syncthreads();   // zeros visible

    for (int t = 0; t < T_STEPS; ++t) {
        // prefetch next step's u into registers (off the critical path)
        float4 un0 = z4, un1 = z4, un2 = z4, un3 = z4;
        if (uok && (t + 1 < T_STEPS)) {
            const float* p = ub + (size_t)(t + 1) * ustep;
            un0 = *(const float4*)(p);
            un1 = *(const float4*)(p + UC);
            un2 = *(const float4*)(p + 2 * UC);
            un3 = *(const float4*)(p + 3 * UC);
        }

        // register sliding window over rows: w2 = row R-2, w1 = row R-1
        const int rm2 = (y0 + 62) & 63;
        const int rm1 = (y0 + 63) & 63;
        float4 w2l = *(const float4*)(hold + rm2 * HSTR + xlo);
        float4 w2h = *(const float4*)(hold + rm2 * HSTR + xc);
        float4 w1l = *(const float4*)(hold + rm1 * HSTR + xlo);
        float4 w1h = *(const float4*)(hold + rm1 * HSTR + xc);

#pragma unroll
        for (int r = 0; r < 4; ++r) {
            const int R = y0 + r;
            float4 w0l = *(const float4*)(hold + R * HSTR + xlo);
            float4 w0h = *(const float4*)(hold + R * HSTR + xc);

            // combined 8-col windows: c[0..3] = cols xc-4..xc-1, c[4..7] = xc..xc+3
            float c0[8] = {w0l.x, w0l.y, w0l.z, w0l.w, w0h.x, w0h.y, w0h.z, w0h.w};
            float c1[8] = {w1l.x, w1l.y, w1l.z, w1l.w, w1h.x, w1h.y, w1h.z, w1h.w};
            float c2[8] = {w2l.x, w2l.y, w2l.z, w2l.w, w2h.x, w2h.y, w2h.z, w2h.w};

            float uu[4] = {0.f, 0.f, 0.f, 0.f};
            {
                const float4 us = (r == 0) ? uc0 : (r == 1) ? uc1 : (r == 2) ? uc2 : uc3;
                uu[0] = us.x; uu[1] = us.y; uu[2] = us.z; uu[3] = us.w;
            }

            float acc[4];
#pragma unroll
            for (int j = 0; j < 4; ++j) {
                acc[j] = a[0] * c0[4 + j] + a[1] * c0[3 + j] + a[2] * c0[2 + j]
                       + a[3] * c1[4 + j] + a[4] * c1[3 + j] + a[5] * c1[2 + j]
                       + a[6] * c2[4 + j] + a[7] * c2[3 + j] + a[8] * c2[2 + j]
                       + uu[j];
            }

            *(float4*)(hnew + R * HSTR + xc) =
                make_float4(acc[0], acc[1], acc[2], acc[3]);

            if (R < HW && xc < HW) {
                *(float4*)(og + (size_t)t * ostep + R * HW + xc) =
                    make_float4(acc[0], acc[1], acc[2], acc[3]);
            }

            // slide
            w2l = w1l; w2h = w1h;
            w1l = w0l; w1h = w0h;
        }

        __syncthreads();   // hnew complete + all reads of hold done

        float* tmp = hold; hold = hnew; hnew = tmp;
        uc0 = un0; uc1 = un1; uc2 = un2; uc3 = un3;
    }
}

// ---------------- Fallback (round-1 kernel, known-correct) ------------------
__global__ __launch_bounds__(256)
void convssm_scan_fused(const float* __restrict__ x_seq,
                        const float* __restrict__ A_k,
                        const float* __restrict__ B_k,
                        float* __restrict__ out)
{
    __shared__ float h0[N][N];
    __shared__ float h1[N][N];
    __shared__ float xs[N][N];

    const int bc = blockIdx.x;
    const int b  = bc >> 5;
    const int c  = bc & 31;
    const int tid = threadIdx.x;
    const int x   = tid & 63;
    const int y0  = (tid >> 6) << 4;

    float a[9], bw[9];
#pragma unroll
    for (int i = 0; i < 9; ++i) { a[i] = A_k[c*9+i]; bw[i] = B_k[c*9+i]; }

#pragma unroll
    for (int r = 0; r < 16; ++r) { h0[y0+r][x] = 0.f; xs[y0+r][x] = 0.f; }

    float (*hold)[N] = h0;
    float (*hnew)[N] = h1;
    const int xm1 = (x + 63) & 63, xm2 = (x + 62) & 63;
    const size_t img = (size_t)HW*HW, tstr = (size_t)B_DIM*C_DIM*img;
    const float* xbase = x_seq + ((size_t)b*C_DIM + c)*img;
    float* obase = out + ((size_t)b*C_DIM + c)*img;
    const bool loader = (x < HW);

    for (int t = 0; t < T_STEPS; ++t) {
        if (loader) {
#pragma unroll
            for (int r = 0; r < 16; ++r) {
                int yy = y0 + r;
                if (yy < HW) xs[yy][x] = xbase[(size_t)t*tstr + yy*HW + x];
            }
        }
        __syncthreads();
        const int ym1 = (y0 + N - 1) & 63, ym2 = (y0 + N - 2) & 63;
        float hr1c0 = hold[ym1][x], hr1c1 = hold[ym1][xm1], hr1c2 = hold[ym1][xm2];
        float hr2c0 = hold[ym2][x], hr2c1 = hold[ym2][xm1], hr2c2 = hold[ym2][xm2];
        float sr1c0 = xs[ym1][x], sr1c1 = xs[ym1][xm1], sr1c2 = xs[ym1][xm2];
        float sr2c0 = xs[ym2][x], sr2c1 = xs[ym2][xm1], sr2c2 = xs[ym2][xm2];
#pragma unroll
        for (int r = 0; r < 16; ++r) {
            const int yy = y0 + r;
            float hr0c0 = hold[yy][x], hr0c1 = hold[yy][xm1], hr0c2 = hold[yy][xm2];
            float sr0c0 = xs[yy][x], sr0c1 = xs[yy][xm1], sr0c2 = xs[yy][xm2];
            float v = a[0]*hr0c0 + a[1]*hr0c1 + a[2]*hr0c2
                    + a[3]*hr1c0 + a[4]*hr1c1 + a[5]*hr1c2
                    + a[6]*hr2c0 + a[7]*hr2c1 + a[8]*hr2c2
                    + bw[0]*sr0c0 + bw[1]*sr0c1 + bw[2]*sr0c2
                    + bw[3]*sr1c0 + bw[4]*sr1c1 + bw[5]*sr1c2
                    + bw[6]*sr2c0 + bw[7]*sr2c1 + bw[8]*sr2c2;
            hnew[yy][x] = v;
            if (yy < HW && x < HW) obase[(size_t)t*tstr + yy*HW + x] = v;
            hr2c0=hr1c0; hr2c1=hr1c1; hr2c2=hr1c2;
            hr1c0=hr0c0; hr1c1=hr0c1; hr1c2=hr0c2;
            sr2c0=sr1c0; sr2c1=sr1c1; sr2c2=sr1c2;
            sr1c0=sr0c0; sr1c1=sr0c1; sr1c2=sr0c2;
        }
        __syncthreads();
        float (*tmp)[N] = hold; hold = hnew; hnew = tmp;
    }
}

extern "C" void kernel_launch(void* const* d_in, const int* in_sizes, int n_in,
                              void* d_out, int out_size, void* d_ws, size_t ws_size,
                              hipStream_t stream)
{
    const float* x_seq = (const float*)d_in[0];
    const float* A_k   = (const float*)d_in[1];
    const float* B_k   = (const float*)d_in[2];
    float* out = (float*)d_out;

    const size_t need = (size_t)T_STEPS * B_DIM * C_DIM * UIMG * sizeof(float);
    if (ws_size >= need) {
        float* u = (float*)d_ws;
        convssm_pass1<<<dim3(T_STEPS * B_DIM * C_DIM), dim3(256), 0, stream>>>(
            x_seq, B_k, u);
        convssm_scan2<<<dim3(B_DIM * C_DIM), dim3(256), 0, stream>>>(
            u, A_k, out);
    } else {
        convssm_scan_fused<<<dim3(B_DIM * C_DIM), dim3(256), 0, stream>>>(
            x_seq, A_k, B_k, out);
    }
}

// Round 3
// 74.901 us; speedup vs baseline: 3.1687x; 1.0940x over previous
//
#include <hip/hip_runtime.h>

// ConvSSM scan, spatial domain, step-doubled.
//   h_t = A (*) h_{t-1} + u_t,  u_t = B (*) xpad_t,  (*) = circular conv on 64x64.
// Define H_m = h_{2m+1}:
//   H_m   = A2 (*) H_{m-1} + G_m,   A2 = A(*)A (5x5),  G_m = A(*)u_{2m} + u_{2m+1}
//   h_2m  = A  (*) H_{m-1} + u_{2m}   (even emit, reuses same LDS window)
// Pass 1 (2048 parallel blocks): U_m = u_{2m} (34x36), G_m (36x36) -> d_ws.
// Pass 2 (64 blocks): 32-step scan, h in LDS dbuf, 8x8 register window/thread.

constexpr int T_STEPS = 64;
constexpr int B_DIM   = 2;
constexpr int C_DIM   = 32;
constexpr int HW      = 32;
constexpr int N       = 64;
constexpr int NIMG    = B_DIM * C_DIM;   // 64
constexpr int MH      = T_STEPS / 2;     // 32 scan steps
constexpr int HSTR    = 68;              // LDS row stride (floats)
constexpr int UCOL    = 36;
constexpr int USZ     = 34 * UCOL;       // 1224 floats
constexpr int GSZ     = 36 * 36;         // 1296 floats

// ---------------- Pass 1: U_m, G_m per (m, b, c) -----------------------------
__global__ __launch_bounds__(256)
void convssm_pass1b(const float* __restrict__ x_seq,  // (T,B,C,32,32)
                    const float* __restrict__ A_k,    // (C,3,3)
                    const float* __restrict__ B_k,    // (C,3,3)
                    float* __restrict__ U,            // (NIMG*MH, 34, 36) idx bc*MH+m
                    float* __restrict__ G)            // (NIMG*MH, 36, 36)
{
    __shared__ float xe[32][33];
    __shared__ float xo[32][33];
    __shared__ float ue[34][35];

    const int blk = blockIdx.x;           // m*64 + bc
    const int m   = blk >> 6;
    const int bc  = blk & 63;
    const int c   = bc & 31;
    const int tid = threadIdx.x;

    float a[9], bw[9];
#pragma unroll
    for (int i = 0; i < 9; ++i) { a[i] = A_k[c * 9 + i]; bw[i] = B_k[c * 9 + i]; }

    const float* xE = x_seq + ((size_t)(2 * m)     * NIMG + bc) * (HW * HW);
    const float* xO = x_seq + ((size_t)(2 * m + 1) * NIMG + bc) * (HW * HW);
#pragma unroll
    for (int k = 0; k < 4; ++k) {
        int i = tid + k * 256;
        int y = i >> 5, xx = i & 31;
        xe[y][xx] = xE[i];
        xo[y][xx] = xO[i];
    }
    __syncthreads();

    // U_m = B (*) xpad_{2m}: support rows/cols 0..33; stored 34x36 (cols 34,35 = 0)
    float* Ug = U + (size_t)(bc * MH + m) * USZ;
    for (int i = tid; i < USZ; i += 256) {
        int y = i / UCOL, xx = i - y * UCOL;
        float v = 0.0f;
        if (xx < 34) {
#pragma unroll
            for (int ky = 0; ky < 3; ++ky) {
                int yy = y - ky;
                if (yy < 0 || yy >= 32) continue;
#pragma unroll
                for (int kx = 0; kx < 3; ++kx) {
                    int xs = xx - kx;
                    if (xs < 0 || xs >= 32) continue;
                    v += bw[ky * 3 + kx] * xe[yy][xs];
                }
            }
        }
        if (xx < 35) ue[y][xx] = v;
        Ug[i] = v;
    }
    __syncthreads();

    // G_m = B (*) xpad_{2m+1} + A (*) U_m : support 36x36
    float* Gg = G + (size_t)(bc * MH + m) * GSZ;
    for (int i = tid; i < GSZ; i += 256) {
        int y = i / 36, xx = i - y * 36;
        float v = 0.0f;
#pragma unroll
        for (int ky = 0; ky < 3; ++ky) {
#pragma unroll
            for (int kx = 0; kx < 3; ++kx) {
                int yy = y - ky, xs = xx - kx;
                if (yy >= 0 && yy < 32 && xs >= 0 && xs < 32)
                    v += bw[ky * 3 + kx] * xo[yy][xs];
                if (yy >= 0 && yy < 34 && xs >= 0 && xs < 34)
                    v += a[ky * 3 + kx] * ue[yy][xs];
            }
        }
        Gg[i] = v;
    }
}

// ---------------- Pass 2: 32-step scan with A^2 ------------------------------
__global__ __launch_bounds__(256, 1)
void convssm_scan3(const float* __restrict__ U,
                   const float* __restrict__ G,
                   const float* __restrict__ A_k,
                   float* __restrict__ out)          // (T,B,C,32,32)
{
    __shared__ __align__(16) float hbuf[2][N * HSTR];

    const int bc  = blockIdx.x;          // 0..63
    const int c   = bc & 31;
    const int tid = threadIdx.x;
    const int g   = tid & 15;
    const int s   = tid >> 4;
    const int y0  = s * 4;
    const int xc  = g * 4;
    const int xlo = (xc + 60) & 63;      // xc-4 mod 64

    float a[9];
#pragma unroll
    for (int i = 0; i < 9; ++i) a[i] = A_k[c * 9 + i];

    // A2 = A (*) A, 5x5
    float a2[5][5];
#pragma unroll
    for (int p = 0; p < 5; ++p) {
#pragma unroll
        for (int q = 0; q < 5; ++q) {
            float v = 0.0f;
#pragma unroll
            for (int ky = 0; ky < 3; ++ky) {
                int py = p - ky;
                if (py < 0 || py > 2) continue;
#pragma unroll
                for (int kx = 0; kx < 3; ++kx) {
                    int qx = q - kx;
                    if (qx < 0 || qx > 2) continue;
                    v += a[ky * 3 + kx] * a[py * 3 + qx];
                }
            }
            a2[p][q] = v;
        }
    }

    for (int i = tid; i < N * HSTR; i += 256) hbuf[0][i] = 0.0f;

    const bool gok   = (y0 <= 32) && (xc <= 32);   // G rows/cols y0..y0+3 < 36
    const bool cropw = (y0 < HW);                  // wave-uniform
    const bool crop  = cropw && (xc < HW);

    const float* Ub = U + (size_t)bc * MH * USZ + y0 * UCOL + xc;
    const float* Gb = G + (size_t)bc * MH * GSZ + y0 * 36 + xc;

    const float4 z4 = make_float4(0.f, 0.f, 0.f, 0.f);
    float4 gc0 = z4, gc1 = z4, gc2 = z4, gc3 = z4;
    float4 uc0 = z4, uc1 = z4, uc2 = z4, uc3 = z4;
    if (gok) {
        gc0 = *(const float4*)(Gb);
        gc1 = *(const float4*)(Gb + 36);
        gc2 = *(const float4*)(Gb + 72);
        gc3 = *(const float4*)(Gb + 108);
    }
    if (crop) {
        uc0 = *(const float4*)(Ub);
        uc1 = *(const float4*)(Ub + UCOL);
        uc2 = *(const float4*)(Ub + 2 * UCOL);
        uc3 = *(const float4*)(Ub + 3 * UCOL);
    }

    float* hold = &hbuf[0][0];
    float* hnew = &hbuf[1][0];
    float* ob   = out + (size_t)bc * (HW * HW);
    const size_t tstr = (size_t)NIMG * (HW * HW);  // 65536

    __syncthreads();

    for (int m = 0; m < MH; ++m) {
        // prefetch next step's G / U
        float4 gn0 = z4, gn1 = z4, gn2 = z4, gn3 = z4;
        float4 un0 = z4, un1 = z4, un2 = z4, un3 = z4;
        if (m + 1 < MH) {
            if (gok) {
                const float* p = Gb + (size_t)(m + 1) * GSZ;
                gn0 = *(const float4*)(p);
                gn1 = *(const float4*)(p + 36);
                gn2 = *(const float4*)(p + 72);
                gn3 = *(const float4*)(p + 108);
            }
            if (crop) {
                const float* p = Ub + (size_t)(m + 1) * USZ;
                un0 = *(const float4*)(p);
                un1 = *(const float4*)(p + UCOL);
                un2 = *(const float4*)(p + 2 * UCOL);
                un3 = *(const float4*)(p + 3 * UCOL);
            }
        }

        // 8x8 register window: rows (y0-4 .. y0+3) mod 64, cols (xc-4 .. xc+3) mod 64
        float w[8][8];
#pragma unroll
        for (int i = 0; i < 8; ++i) {
            const int R = (y0 - 4 + i) & 63;
            const float4 lo = *(const float4*)(hold + R * HSTR + xlo);
            const float4 hi = *(const float4*)(hold + R * HSTR + xc);
            w[i][0] = lo.x; w[i][1] = lo.y; w[i][2] = lo.z; w[i][3] = lo.w;
            w[i][4] = hi.x; w[i][5] = hi.y; w[i][6] = hi.z; w[i][7] = hi.w;
        }

        // H_new = A2 (*) H_old + G
        float acc[4][4];
        acc[0][0] = gc0.x; acc[0][1] = gc0.y; acc[0][2] = gc0.z; acc[0][3] = gc0.w;
        acc[1][0] = gc1.x; acc[1][1] = gc1.y; acc[1][2] = gc1.z; acc[1][3] = gc1.w;
        acc[2][0] = gc2.x; acc[2][1] = gc2.y; acc[2][2] = gc2.z; acc[2][3] = gc2.w;
        acc[3][0] = gc3.x; acc[3][1] = gc3.y; acc[3][2] = gc3.z; acc[3][3] = gc3.w;
#pragma unroll
        for (int r = 0; r < 4; ++r) {
#pragma unroll
            for (int p = 0; p < 5; ++p) {
                const int i = r + 4 - p;          // window row for (y0+r) - p
#pragma unroll
                for (int q = 0; q < 5; ++q) {
                    const float cf = a2[p][q];
#pragma unroll
                    for (int j = 0; j < 4; ++j)
                        acc[r][j] += cf * w[i][4 + j - q];
                }
            }
        }

        // write new state to LDS
#pragma unroll
        for (int r = 0; r < 4; ++r)
            *(float4*)(hnew + (y0 + r) * HSTR + xc) =
                make_float4(acc[r][0], acc[r][1], acc[r][2], acc[r][3]);

        // even emit: h_{2m} = A (*) H_old + u_{2m}  (crop region only)
        if (cropw) {
            float E[4][4];
            E[0][0] = uc0.x; E[0][1] = uc0.y; E[0][2] = uc0.z; E[0][3] = uc0.w;
            E[1][0] = uc1.x; E[1][1] = uc1.y; E[1][2] = uc1.z; E[1][3] = uc1.w;
            E[2][0] = uc2.x; E[2][1] = uc2.y; E[2][2] = uc2.z; E[2][3] = uc2.w;
            E[3][0] = uc3.x; E[3][1] = uc3.y; E[3][2] = uc3.z; E[3][3] = uc3.w;
#pragma unroll
            for (int r = 0; r < 4; ++r) {
#pragma unroll
                for (int ky = 0; ky < 3; ++ky) {
                    const int i = r + 4 - ky;
#pragma unroll
                    for (int kx = 0; kx < 3; ++kx) {
                        const float cf = a[ky * 3 + kx];
#pragma unroll
                        for (int j = 0; j < 4; ++j)
                            E[r][j] += cf * w[i][4 + j - kx];
                    }
                }
            }
            if (crop) {
                float* oe = ob + (size_t)(2 * m) * tstr;
                float* oo = oe + tstr;
#pragma unroll
                for (int r = 0; r < 4; ++r) {
                    *(float4*)(oe + (y0 + r) * HW + xc) =
                        make_float4(E[r][0], E[r][1], E[r][2], E[r][3]);
                    *(float4*)(oo + (y0 + r) * HW + xc) =
                        make_float4(acc[r][0], acc[r][1], acc[r][2], acc[r][3]);
                }
            }
        }

        __syncthreads();   // hnew complete; all reads of hold done

        float* tmp = hold; hold = hnew; hnew = tmp;
        gc0 = gn0; gc1 = gn1; gc2 = gn2; gc3 = gn3;
        uc0 = un0; uc1 = un1; uc2 = un2; uc3 = un3;
    }
}

// ---------------- Fallback (round-1 fused, known-correct) --------------------
__global__ __launch_bounds__(256)
void convssm_scan_fused(const float* __restrict__ x_seq,
                        const float* __restrict__ A_k,
                        const float* __restrict__ B_k,
                        float* __restrict__ out)
{
    __shared__ float h0[N][N];
    __shared__ float h1[N][N];
    __shared__ float xs[N][N];

    const int bc = blockIdx.x;
    const int b  = bc >> 5;
    const int c  = bc & 31;
    const int tid = threadIdx.x;
    const int x   = tid & 63;
    const int y0  = (tid >> 6) << 4;

    float a[9], bw[9];
#pragma unroll
    for (int i = 0; i < 9; ++i) { a[i] = A_k[c*9+i]; bw[i] = B_k[c*9+i]; }
#pragma unroll
    for (int r = 0; r < 16; ++r) { h0[y0+r][x] = 0.f; xs[y0+r][x] = 0.f; }

    float (*hold)[N] = h0;
    float (*hnew)[N] = h1;
    const int xm1 = (x + 63) & 63, xm2 = (x + 62) & 63;
    const size_t img = (size_t)HW*HW, tstr = (size_t)NIMG*img;
    const float* xbase = x_seq + ((size_t)b*C_DIM + c)*img;
    float* obase = out + ((size_t)b*C_DIM + c)*img;
    const bool loader = (x < HW);

    for (int t = 0; t < T_STEPS; ++t) {
        if (loader) {
#pragma unroll
            for (int r = 0; r < 16; ++r) {
                int yy = y0 + r;
                if (yy < HW) xs[yy][x] = xbase[(size_t)t*tstr + yy*HW + x];
            }
        }
        __syncthreads();
        const int ym1 = (y0 + N - 1) & 63, ym2 = (y0 + N - 2) & 63;
        float hr1c0 = hold[ym1][x], hr1c1 = hold[ym1][xm1], hr1c2 = hold[ym1][xm2];
        float hr2c0 = hold[ym2][x], hr2c1 = hold[ym2][xm1], hr2c2 = hold[ym2][xm2];
        float sr1c0 = xs[ym1][x], sr1c1 = xs[ym1][xm1], sr1c2 = xs[ym1][xm2];
        float sr2c0 = xs[ym2][x], sr2c1 = xs[ym2][xm1], sr2c2 = xs[ym2][xm2];
#pragma unroll
        for (int r = 0; r < 16; ++r) {
            const int yy = y0 + r;
            float hr0c0 = hold[yy][x], hr0c1 = hold[yy][xm1], hr0c2 = hold[yy][xm2];
            float sr0c0 = xs[yy][x], sr0c1 = xs[yy][xm1], sr0c2 = xs[yy][xm2];
            float v = a[0]*hr0c0 + a[1]*hr0c1 + a[2]*hr0c2
                    + a[3]*hr1c0 + a[4]*hr1c1 + a[5]*hr1c2
                    + a[6]*hr2c0 + a[7]*hr2c1 + a[8]*hr2c2
                    + bw[0]*sr0c0 + bw[1]*sr0c1 + bw[2]*sr0c2
                    + bw[3]*sr1c0 + bw[4]*sr1c1 + bw[5]*sr1c2
                    + bw[6]*sr2c0 + bw[7]*sr2c1 + bw[8]*sr2c2;
            hnew[yy][x] = v;
            if (yy < HW && x < HW) obase[(size_t)t*tstr + yy*HW + x] = v;
            hr2c0=hr1c0; hr2c1=hr1c1; hr2c2=hr1c2;
            hr1c0=hr0c0; hr1c1=hr0c1; hr1c2=hr0c2;
            sr2c0=sr1c0; sr2c1=sr1c1; sr2c2=sr1c2;
            sr1c0=sr0c0; sr1c1=sr0c1; sr1c2=sr0c2;
        }
        __syncthreads();
        float (*tmp)[N] = hold; hold = hnew; hnew = tmp;
    }
}

extern "C" void kernel_launch(void* const* d_in, const int* in_sizes, int n_in,
                              void* d_out, int out_size, void* d_ws, size_t ws_size,
                              hipStream_t stream)
{
    const float* x_seq = (const float*)d_in[0];
    const float* A_k   = (const float*)d_in[1];
    const float* B_k   = (const float*)d_in[2];
    float* out = (float*)d_out;

    const size_t needU = (size_t)NIMG * MH * USZ;             // floats
    const size_t needG = (size_t)NIMG * MH * GSZ;
    const size_t need  = (needU + needG) * sizeof(float);     // ~20.6 MB

    if (ws_size >= need) {
        float* U = (float*)d_ws;
        float* G = U + needU;
        convssm_pass1b<<<dim3(MH * NIMG), dim3(256), 0, stream>>>(
            x_seq, A_k, B_k, U, G);
        convssm_scan3<<<dim3(NIMG), dim3(256), 0, stream>>>(
            U, G, A_k, out);
    } else {
        convssm_scan_fused<<<dim3(NIMG), dim3(256), 0, stream>>>(
            x_seq, A_k, B_k, out);
    }
}

// Round 4
// 60.708 us; speedup vs baseline: 3.9095x; 1.2338x over previous
//
#include <hip/hip_runtime.h>

// ConvSSM scan, spatial domain, step-doubled, 512-thread scan (2 waves/SIMD).
//   h_t = A (*) h_{t-1} + u_t,  u_t = B (*) xpad_t,  (*) = circular conv on 64x64.
// H_m = h_{2m+1}:
//   H_m  = A2 (*) H_{m-1} + G_m,  A2 = A(*)A (5x5),  G_m = A(*)u_{2m} + u_{2m+1}
//   h_2m = A  (*) H_{m-1} + u_{2m}   (even emit, crop region only)
// Pass 1 (2048 blocks): U_m = u_{2m} cropped to 32x32, G_m (36x36) -> d_ws.
// Pass 2 (64 blocks x 512 thr): 32-step scan, h in LDS dbuf, 6x8 window / 2x4 tile.

constexpr int T_STEPS = 64;
constexpr int B_DIM   = 2;
constexpr int C_DIM   = 32;
constexpr int HW      = 32;
constexpr int N       = 64;
constexpr int NIMG    = B_DIM * C_DIM;   // 64
constexpr int MH      = T_STEPS / 2;     // 32 scan steps
constexpr int HSTR    = 68;              // LDS row stride (floats)
constexpr int GSZ     = 36 * 36;         // 1296 floats
constexpr int USZ     = HW * HW;         // 1024 floats (cropped u_even)

// ---------------- Pass 1: U_m (32x32), G_m (36x36) per (m, bc) ---------------
__global__ __launch_bounds__(256)
void convssm_pass1c(const float* __restrict__ x_seq,  // (T,B,C,32,32)
                    const float* __restrict__ A_k,    // (C,3,3)
                    const float* __restrict__ B_k,    // (C,3,3)
                    float* __restrict__ U,            // (NIMG*MH, 32, 32) idx bc*MH+m
                    float* __restrict__ G)            // (NIMG*MH, 36, 36)
{
    __shared__ float xe[32][33];
    __shared__ float xo[32][33];
    __shared__ float ue[34][35];

    const int blk = blockIdx.x;           // m*64 + bc
    const int m   = blk >> 6;
    const int bc  = blk & 63;
    const int c   = bc & 31;
    const int tid = threadIdx.x;

    float a[9], bw[9];
#pragma unroll
    for (int i = 0; i < 9; ++i) { a[i] = A_k[c * 9 + i]; bw[i] = B_k[c * 9 + i]; }

    const float* xE = x_seq + ((size_t)(2 * m)     * NIMG + bc) * (HW * HW);
    const float* xO = x_seq + ((size_t)(2 * m + 1) * NIMG + bc) * (HW * HW);
#pragma unroll
    for (int k = 0; k < 4; ++k) {
        int i = tid + k * 256;
        int y = i >> 5, xx = i & 31;
        xe[y][xx] = xE[i];
        xo[y][xx] = xO[i];
    }
    __syncthreads();

    // ue = B (*) xpad_{2m} over 34x34; crop (32x32) -> U
    float* Ug = U + (size_t)(bc * MH + m) * USZ;
    for (int i = tid; i < 34 * 34; i += 256) {
        int y = i / 34, xx = i - y * 34;
        float v = 0.0f;
#pragma unroll
        for (int ky = 0; ky < 3; ++ky) {
            int yy = y - ky;
            if (yy < 0 || yy >= 32) continue;
#pragma unroll
            for (int kx = 0; kx < 3; ++kx) {
                int xs = xx - kx;
                if (xs < 0 || xs >= 32) continue;
                v += bw[ky * 3 + kx] * xe[yy][xs];
            }
        }
        ue[y][xx] = v;
        if (y < 32 && xx < 32) Ug[y * 32 + xx] = v;
    }
    __syncthreads();

    // G_m = B (*) xpad_{2m+1} + A (*) ue : support 36x36
    float* Gg = G + (size_t)(bc * MH + m) * GSZ;
    for (int i = tid; i < GSZ; i += 256) {
        int y = i / 36, xx = i - y * 36;
        float v = 0.0f;
#pragma unroll
        for (int ky = 0; ky < 3; ++ky) {
#pragma unroll
            for (int kx = 0; kx < 3; ++kx) {
                int yy = y - ky, xs = xx - kx;
                if (yy >= 0 && yy < 32 && xs >= 0 && xs < 32)
                    v += bw[ky * 3 + kx] * xo[yy][xs];
                if (yy >= 0 && yy < 34 && xs >= 0 && xs < 34)
                    v += a[ky * 3 + kx] * ue[yy][xs];
            }
        }
        Gg[i] = v;
    }
}

// ---------------- Pass 2: 32-step scan, 512 threads --------------------------
__global__ __launch_bounds__(512, 2)
void convssm_scan4(const float* __restrict__ U,
                   const float* __restrict__ G,
                   const float* __restrict__ A_k,
                   float* __restrict__ out)          // (T,B,C,32,32)
{
    __shared__ __align__(16) float hbuf[2][N * HSTR];

    const int bc  = blockIdx.x;          // 0..63
    const int c   = bc & 31;
    const int tid = threadIdx.x;
    const int g   = tid & 15;            // col group: cols 4g..4g+3
    const int s   = tid >> 4;            // 0..31: rows 2s, 2s+1
    const int y0  = s * 2;
    const int xc  = g * 4;
    const int xlo = (xc + 60) & 63;      // xc-4 mod 64

    float a[9];
#pragma unroll
    for (int i = 0; i < 9; ++i) a[i] = A_k[c * 9 + i];

    // A2 = A (*) A, 5x5
    float a2[5][5];
#pragma unroll
    for (int p = 0; p < 5; ++p) {
#pragma unroll
        for (int q = 0; q < 5; ++q) {
            float v = 0.0f;
#pragma unroll
            for (int ky = 0; ky < 3; ++ky) {
                int py = p - ky;
                if (py < 0 || py > 2) continue;
#pragma unroll
                for (int kx = 0; kx < 3; ++kx) {
                    int qx = q - kx;
                    if (qx < 0 || qx > 2) continue;
                    v += a[ky * 3 + kx] * a[py * 3 + qx];
                }
            }
            a2[p][q] = v;
        }
    }

    for (int i = tid; i < N * HSTR; i += 512) hbuf[0][i] = 0.0f;

    const bool gok   = (y0 <= 34) && (xc <= 32);   // G rows y0,y0+1 / cols xc..xc+3 < 36
    const bool cropw = (y0 < HW);
    const bool crop  = cropw && (xc < HW);

    const float* Ub = U + (size_t)bc * MH * USZ + y0 * HW + xc;
    const float* Gb = G + (size_t)bc * MH * GSZ + y0 * 36 + xc;

    const float4 z4 = make_float4(0.f, 0.f, 0.f, 0.f);
    float4 gc0 = z4, gc1 = z4, uc0 = z4, uc1 = z4;
    if (gok) {
        gc0 = *(const float4*)(Gb);
        gc1 = *(const float4*)(Gb + 36);
    }
    if (crop) {
        uc0 = *(const float4*)(Ub);
        uc1 = *(const float4*)(Ub + HW);
    }

    float* hold = &hbuf[0][0];
    float* hnew = &hbuf[1][0];
    float* ob   = out + (size_t)bc * (HW * HW);
    const size_t tstr = (size_t)NIMG * (HW * HW);  // 65536

    __syncthreads();

    for (int m = 0; m < MH; ++m) {
        // prefetch next step's G / U (off the critical path)
        float4 gn0 = z4, gn1 = z4, un0 = z4, un1 = z4;
        if (m + 1 < MH) {
            if (gok) {
                const float* p = Gb + (size_t)(m + 1) * GSZ;
                gn0 = *(const float4*)(p);
                gn1 = *(const float4*)(p + 36);
            }
            if (crop) {
                const float* p = Ub + (size_t)(m + 1) * USZ;
                un0 = *(const float4*)(p);
                un1 = *(const float4*)(p + HW);
            }
        }

        // 6x8 register window: rows (y0-4 .. y0+1) mod 64, cols (xc-4 .. xc+3) mod 64
        float w[6][8];
#pragma unroll
        for (int i = 0; i < 6; ++i) {
            const int R = (y0 - 4 + i) & 63;
            const float4 lo = *(const float4*)(hold + R * HSTR + xlo);
            const float4 hi = *(const float4*)(hold + R * HSTR + xc);
            w[i][0] = lo.x; w[i][1] = lo.y; w[i][2] = lo.z; w[i][3] = lo.w;
            w[i][4] = hi.x; w[i][5] = hi.y; w[i][6] = hi.z; w[i][7] = hi.w;
        }

        // H_new = A2 (*) H_old + G  (2 rows x 4 cols)
        float acc[2][4];
        acc[0][0] = gc0.x; acc[0][1] = gc0.y; acc[0][2] = gc0.z; acc[0][3] = gc0.w;
        acc[1][0] = gc1.x; acc[1][1] = gc1.y; acc[1][2] = gc1.z; acc[1][3] = gc1.w;
#pragma unroll
        for (int r = 0; r < 2; ++r) {
#pragma unroll
            for (int p = 0; p < 5; ++p) {
                const int i = r + 4 - p;
#pragma unroll
                for (int q = 0; q < 5; ++q) {
                    const float cf = a2[p][q];
#pragma unroll
                    for (int j = 0; j < 4; ++j)
                        acc[r][j] += cf * w[i][4 + j - q];
                }
            }
        }

        *(float4*)(hnew + y0 * HSTR + xc) =
            make_float4(acc[0][0], acc[0][1], acc[0][2], acc[0][3]);
        *(float4*)(hnew + (y0 + 1) * HSTR + xc) =
            make_float4(acc[1][0], acc[1][1], acc[1][2], acc[1][3]);

        // even emit: h_{2m} = A (*) H_old + u_{2m}  (crop region only)
        if (cropw) {
            float E[2][4];
            E[0][0] = uc0.x; E[0][1] = uc0.y; E[0][2] = uc0.z; E[0][3] = uc0.w;
            E[1][0] = uc1.x; E[1][1] = uc1.y; E[1][2] = uc1.z; E[1][3] = uc1.w;
#pragma unroll
            for (int r = 0; r < 2; ++r) {
#pragma unroll
                for (int ky = 0; ky < 3; ++ky) {
                    const int i = r + 4 - ky;
#pragma unroll
                    for (int kx = 0; kx < 3; ++kx) {
                        const float cf = a[ky * 3 + kx];
#pragma unroll
                        for (int j = 0; j < 4; ++j)
                            E[r][j] += cf * w[i][4 + j - kx];
                    }
                }
            }
            if (crop) {
                float* oe = ob + (size_t)(2 * m) * tstr;
                float* oo = oe + tstr;
#pragma unroll
                for (int r = 0; r < 2; ++r) {
                    *(float4*)(oe + (y0 + r) * HW + xc) =
                        make_float4(E[r][0], E[r][1], E[r][2], E[r][3]);
                    *(float4*)(oo + (y0 + r) * HW + xc) =
                        make_float4(acc[r][0], acc[r][1], acc[r][2], acc[r][3]);
                }
            }
        }

        __syncthreads();   // hnew complete; all reads of hold done

        float* tmp = hold; hold = hnew; hnew = tmp;
        gc0 = gn0; gc1 = gn1;
        uc0 = un0; uc1 = un1;
    }
}

// ---------------- Fallback (round-1 fused, known-correct) --------------------
__global__ __launch_bounds__(256)
void convssm_scan_fused(const float* __restrict__ x_seq,
                        const float* __restrict__ A_k,
                        const float* __restrict__ B_k,
                        float* __restrict__ out)
{
    __shared__ float h0[N][N];
    __shared__ float h1[N][N];
    __shared__ float xs[N][N];

    const int bc = blockIdx.x;
    const int b  = bc >> 5;
    const int c  = bc & 31;
    const int tid = threadIdx.x;
    const int x   = tid & 63;
    const int y0  = (tid >> 6) << 4;

    float a[9], bw[9];
#pragma unroll
    for (int i = 0; i < 9; ++i) { a[i] = A_k[c*9+i]; bw[i] = B_k[c*9+i]; }
#pragma unroll
    for (int r = 0; r < 16; ++r) { h0[y0+r][x] = 0.f; xs[y0+r][x] = 0.f; }

    float (*hold)[N] = h0;
    float (*hnew)[N] = h1;
    const int xm1 = (x + 63) & 63, xm2 = (x + 62) & 63;
    const size_t img = (size_t)HW*HW, tstr = (size_t)NIMG*img;
    const float* xbase = x_seq + ((size_t)b*C_DIM + c)*img;
    float* obase = out + ((size_t)b*C_DIM + c)*img;
    const bool loader = (x < HW);

    for (int t = 0; t < T_STEPS; ++t) {
        if (loader) {
#pragma unroll
            for (int r = 0; r < 16; ++r) {
                int yy = y0 + r;
                if (yy < HW) xs[yy][x] = xbase[(size_t)t*tstr + yy*HW + x];
            }
        }
        __syncthreads();
        const int ym1 = (y0 + N - 1) & 63, ym2 = (y0 + N - 2) & 63;
        float hr1c0 = hold[ym1][x], hr1c1 = hold[ym1][xm1], hr1c2 = hold[ym1][xm2];
        float hr2c0 = hold[ym2][x], hr2c1 = hold[ym2][xm1], hr2c2 = hold[ym2][xm2];
        float sr1c0 = xs[ym1][x], sr1c1 = xs[ym1][xm1], sr1c2 = xs[ym1][xm2];
        float sr2c0 = xs[ym2][x], sr2c1 = xs[ym2][xm1], sr2c2 = xs[ym2][xm2];
#pragma unroll
        for (int r = 0; r < 16; ++r) {
            const int yy = y0 + r;
            float hr0c0 = hold[yy][x], hr0c1 = hold[yy][xm1], hr0c2 = hold[yy][xm2];
            float sr0c0 = xs[yy][x], sr0c1 = xs[yy][xm1], sr0c2 = xs[yy][xm2];
            float v = a[0]*hr0c0 + a[1]*hr0c1 + a[2]*hr0c2
                    + a[3]*hr1c0 + a[4]*hr1c1 + a[5]*hr1c2
                    + a[6]*hr2c0 + a[7]*hr2c1 + a[8]*hr2c2
                    + bw[0]*sr0c0 + bw[1]*sr0c1 + bw[2]*sr0c2
                    + bw[3]*sr1c0 + bw[4]*sr1c1 + bw[5]*sr1c2
                    + bw[6]*sr2c0 + bw[7]*sr2c1 + bw[8]*sr2c2;
            hnew[yy][x] = v;
            if (yy < HW && x < HW) obase[(size_t)t*tstr + yy*HW + x] = v;
            hr2c0=hr1c0; hr2c1=hr1c1; hr2c2=hr1c2;
            hr1c0=hr0c0; hr1c1=hr0c1; hr1c2=hr0c2;
            sr2c0=sr1c0; sr2c1=sr1c1; sr2c2=sr1c2;
            sr1c0=sr0c0; sr1c1=sr0c1; sr1c2=sr0c2;
        }
        __syncthreads();
        float (*tmp)[N] = hold; hold = hnew; hnew = tmp;
    }
}

extern "C" void kernel_launch(void* const* d_in, const int* in_sizes, int n_in,
                              void* d_out, int out_size, void* d_ws, size_t ws_size,
                              hipStream_t stream)
{
    const float* x_seq = (const float*)d_in[0];
    const float* A_k   = (const float*)d_in[1];
    const float* B_k   = (const float*)d_in[2];
    float* out = (float*)d_out;

    const size_t needU = (size_t)NIMG * MH * USZ;             // floats
    const size_t needG = (size_t)NIMG * MH * GSZ;
    const size_t need  = (needU + needG) * sizeof(float);     // ~19 MB

    if (ws_size >= need) {
        float* U = (float*)d_ws;
        float* G = U + needU;
        convssm_pass1c<<<dim3(MH * NIMG), dim3(256), 0, stream>>>(
            x_seq, A_k, B_k, U, G);
        convssm_scan4<<<dim3(NIMG), dim3(512), 0, stream>>>(
            U, G, A_k, out);
    } else {
        convssm_scan_fused<<<dim3(NIMG), dim3(256), 0, stream>>>(
            x_seq, A_k, B_k, out);
    }
}